// Round 1
// baseline (476.950 us; speedup 1.0000x reference)
//
#include <hip/hip_runtime.h>
#include <math.h>

#define KS 48
#define TLEN 512
#define BN 1024
#define START_S 46
#define STOP_S 47
#define NEGV -10000.0f
#define PF 8     // emission prefetch depth
#define RING 8   // backtrace row prefetch depth (was 4)

typedef float v2f __attribute__((ext_vector_type(2)));

__device__ __forceinline__ float bcast_lane0(float v) {
    return __builtin_bit_cast(float, __builtin_amdgcn_readfirstlane(__builtin_bit_cast(int, v)));
}
__device__ __forceinline__ float rlane(float v, int k) {
    return __builtin_bit_cast(float, __builtin_amdgcn_readlane(__builtin_bit_cast(int, v), k));
}

// wave argmax, first-index tie-break (matches jnp.argmax; validated rounds 1-7)
__device__ __forceinline__ void wargmax(float& bv, int& bi) {
    #pragma unroll
    for (int off = 32; off; off >>= 1) {
        float ov = __shfl_xor(bv, off, 64);
        int   oi = __shfl_xor(bi, off, 64);
        if (ov > bv || (ov == bv && oi < bi)) { bv = ov; bi = oi; }
    }
}

// grid = 2048, 1-wave blocks.
// ROUND-8 CHANGE: the per-step all-to-all state exchange no longer goes through
// LDS (xbuf write + 12x ds_read_b128 = 13 DS ops/step/wave; 8 waves/CU share ONE
// LDS pipe -> ~1k cyc/step CU-level serialization + ~120cy ds latency in the
// serial recurrence chain). Instead: 48x v_readlane -> SGPR, consumed as the
// scalar operand of v_fma/v_add. Identical arithmetic order => bit-exact.
__global__ __launch_bounds__(64) void crf9(
    const float* __restrict__ feats,   // [B, T, K]
    const float* __restrict__ trans,   // [K, K]  trans[next, prev]
    const int*   __restrict__ tags,    // [B, T]
    float*       __restrict__ out,     // [B] nll | [B] path_score | [B*T] paths
    float*       __restrict__ vws)     // [B, T, K] pre-emission max rows B_t
{
    const int lane = threadIdx.x;
    const bool act = lane < KS;

    __shared__ float trans_sh[KS * KS];          // masked trans (backtrace)
    __shared__ unsigned char path_sh[TLEN];

    if (blockIdx.x < BN) {
        // ================= FORWARD (round-4 arithmetic, readlane exchange) =====
        const int b = blockIdx.x;
        const float* fb = feats + (size_t)b * TLEN * KS;
        const int*   tb = tags + (size_t)b * TLEN;

        float Erow[KS];   // exp(masked trans[next=lane][p]); exp(-10000)==0
        {
            const float* tr = trans + (act ? lane : 0) * KS;
            #pragma unroll
            for (int p = 0; p < KS; ++p) {
                float tv = act ? tr[p] : NEGV;
                if (lane == START_S) tv = NEGV;
                if (p == STOP_S)     tv = NEGV;
                Erow[p] = __expf(tv);
            }
        }
        float tstart = act ? trans[lane * KS + START_S] : NEGV;
        if (lane == START_S) tstart = NEGV;

        float alpha = (act ? fb[lane] : -INFINITY) + tstart;   // t=0 peeled, exact

        // scalar chains a0..a3 replicate the old acc0.x/acc0.y/acc1.x/acc1.y
        // fma orders exactly -> bit-identical to the LDS/float4 version.
        auto fstep = [&](float emv) {
            float s  = bcast_lane0(alpha);       // lane-0 alpha finite: valid shift
            float ue = __expf(alpha - s);        // -inf lanes -> 0
            float a0 = 0.f, a1 = 0.f, a2 = 0.f, a3 = 0.f;
            #pragma unroll
            for (int g = 0; g < KS / 4; ++g) {
                float u0 = rlane(ue, 4 * g + 0); // v_readlane -> SGPR (VALU pipe,
                float u1 = rlane(ue, 4 * g + 1); //  not the shared LDS pipe)
                float u2 = rlane(ue, 4 * g + 2);
                float u3 = rlane(ue, 4 * g + 3);
                a0 = __builtin_fmaf(u0, Erow[4 * g + 0], a0);  // v_fma s,v,v
                a1 = __builtin_fmaf(u1, Erow[4 * g + 1], a1);
                a2 = __builtin_fmaf(u2, Erow[4 * g + 2], a2);
                a3 = __builtin_fmaf(u3, Erow[4 * g + 3], a3);
            }
            alpha = emv + s + __logf((a0 + a1) + (a2 + a3));
        };

        float em[PF];
        #pragma unroll
        for (int j = 0; j < PF; ++j)
            em[j] = act ? fb[(1 + j) * KS + lane] : -INFINITY;
        for (int c = 0; c < 63; ++c) {
            const int t0 = 1 + c * PF;
            float em_n[PF];
            #pragma unroll
            for (int j = 0; j < PF; ++j) {
                int tf = t0 + PF + j;
                em_n[j] = (act && tf < TLEN) ? fb[tf * KS + lane] : -INFINITY;
            }
            #pragma unroll
            for (int j = 0; j < PF; ++j) fstep(em[j]);
            #pragma unroll
            for (int j = 0; j < PF; ++j) em[j] = em_n[j];
        }
        #pragma unroll
        for (int j = 0; j < 7; ++j) fstep(em[j]);

        float tstop = act ? trans[STOP_S * KS + lane] : NEGV;
        if (lane == STOP_S) tstop = NEGV;
        float z = alpha + tstop;
        float mz = z;
        #pragma unroll
        for (int off = 32; off; off >>= 1)
            mz = fmaxf(mz, __shfl_xor(mz, off, 64));
        float se = __expf(z - mz);
        #pragma unroll
        for (int off = 32; off; off >>= 1)
            se += __shfl_xor(se, off, 64);
        float logZ = mz + __logf(se);

        float g = 0.0f;
        for (int t = lane; t < TLEN; t += 64) {
            int tg = tb[t];
            int pg = (t == 0) ? START_S : tb[t - 1];
            g += fb[t * KS + tg] + trans[tg * KS + pg];
        }
        #pragma unroll
        for (int off = 32; off; off >>= 1)
            g += __shfl_xor(g, off, 64);
        g += trans[STOP_S * KS + tb[TLEN - 1]];

        if (lane == 0) out[b] = logZ - g;
    } else {
        // ================= VITERBI: max-only scan + ballot backtrace ==========
        const int b = blockIdx.x - BN;
        const float* fb = feats + (size_t)b * TLEN * KS;
        float* vw = vws + (size_t)b * TLEN * KS;

        float Trow[KS];   // masked trans[next=lane][p] — reference's exact add
        {
            const float* tr = trans + (act ? lane : 0) * KS;
            #pragma unroll
            for (int p = 0; p < KS; ++p) {
                float tv = act ? tr[p] : NEGV;
                if (lane == START_S) tv = NEGV;
                if (p == STOP_S)     tv = NEGV;
                Trow[p] = tv;
            }
        }

        float vit = (lane == START_S) ? 0.0f : NEGV;
        float lastB = 0.0f;

        // fp max is exact -> any reduction tree gives bit-identical B.
        // nested fmaxf pairs invite v_max3 fusion; adds w=vit[p]+Trow[p] are
        // per-element, identical to the old pk-add values.
        auto vstep = [&](float emv, int t) {
            float b0 = -3.0e38f, b1 = -3.0e38f;
            #pragma unroll
            for (int g = 0; g < KS / 4; ++g) {
                float w0 = rlane(vit, 4 * g + 0) + Trow[4 * g + 0];
                float w1 = rlane(vit, 4 * g + 1) + Trow[4 * g + 1];
                float w2 = rlane(vit, 4 * g + 2) + Trow[4 * g + 2];
                float w3 = rlane(vit, 4 * g + 3) + Trow[4 * g + 3];
                b0 = fmaxf(fmaxf(b0, w0), w1);   // v_max3 candidates
                b1 = fmaxf(fmaxf(b1, w2), w3);
            }
            float B = fmaxf(b0, b1);             // pre-emission max row
            if (act) vw[t * KS + lane] = B;      // fire-and-forget, coalesced
            lastB = B;
            vit = B + emv;
        };

        float em[PF];
        #pragma unroll
        for (int j = 0; j < PF; ++j)
            em[j] = act ? fb[j * KS + lane] : 0.0f;
        for (int c = 0; c < 64; ++c) {           // 512 = 64*8 exactly
            const int t0 = c * PF;
            float em_n[PF];
            if (c < 63) {
                #pragma unroll
                for (int j = 0; j < PF; ++j)
                    em_n[j] = act ? fb[(t0 + PF + j) * KS + lane] : 0.0f;
            }
            #pragma unroll
            for (int j = 0; j < PF; ++j) vstep(em[j], t0 + j);
            if (c < 63) {
                #pragma unroll
                for (int j = 0; j < PF; ++j) em[j] = em_n[j];
            }
        }

        // drain the scan's fire-and-forget stores before re-reading vw rows
        asm volatile("s_waitcnt vmcnt(0)" ::: "memory");

        // ---- stage masked trans for backtrace (row-major [next][prev]) ----
        for (int idx = lane; idx < KS * KS; idx += 64) {
            int n = idx / KS, p = idx - n * KS;
            float tv = trans[idx];
            if (n == START_S) tv = NEGV;
            if (p == STOP_S)  tv = NEGV;
            trans_sh[idx] = tv;
        }

        float tstop = act ? trans[STOP_S * KS + lane] : NEGV;
        if (lane == STOP_S) tstop = NEGV;

        // terminal: B_{T-1} and e_{T-1} are still live in registers (em[] holds
        // rows 504..511 after the last chunk) -> same values, same ops, no reload.
        float Bcur = lastB;
        float ecur = em[PF - 1];
        float vlast = Bcur + ecur;
        float bv = act ? (vlast + tstop) : -3.0e38f;
        int   bidx = act ? lane : 9999;
        wargmax(bv, bidx);
        int tag = __builtin_amdgcn_readfirstlane(bidx);
        if (lane == 0) {
            out[BN + b] = bv;
            path_sh[TLEN - 1] = (unsigned char)tag;
        }

        // ring prefetch of B and e rows, depth 8 (covers ~1600cy of L3/HBM)
        float Bp[RING], Ep[RING];
        #pragma unroll
        for (int j = 0; j < RING; ++j) {
            int r = TLEN - 2 - j;
            Bp[j] = act ? vw[r * KS + lane] : 0.0f;
            Ep[j] = act ? fb[r * KS + lane] : 0.0f;
        }

        auto btstep = [&](int s) {               // s handles t = TLEN-1-s
            const int slot = s & (RING - 1);
            float Bv = Bp[slot], Ev = Ep[slot];  // row t-1
            int nr = TLEN - 2 - RING - s;
            if (nr >= 0) {
                Bp[slot] = act ? vw[nr * KS + lane] : 0.0f;
                Ep[slot] = act ? fb[nr * KS + lane] : 0.0f;
            }
            float v  = Bv + Ev;                          // v_{t-1}[lane], bit-exact
            float tr = trans_sh[tag * KS + lane];        // uniform row -> 1 ds_read
            float sc = act ? (v + tr) : -INFINITY;       // scan's exact add
            float bt = rlane(Bcur, tag);                 // B_t[tag]
            unsigned long long mk =
                __ballot(sc == bt) & ((1ULL << KS) - 1ULL);
            // first set bit == first-index argmax (exact even under ties)
            tag = __builtin_amdgcn_readfirstlane((int)__builtin_ctzll(mk));
            if (lane == 0) path_sh[TLEN - 2 - s] = (unsigned char)tag;
            Bcur = Bv;
        };
        // 504 = 63*8 exact -> no dynamic-slot epilogue (keeps Bp/Ep in regs);
        // constant-s tail fully unrolled.
        #pragma unroll 8
        for (int s = 0; s < 504; ++s) btstep(s);
        #pragma unroll
        for (int s = 504; s <= TLEN - 2; ++s) btstep(s);

        __syncthreads();   // single wave: just drains LDS before the read-back
        float* pout = out + 2 * BN + (size_t)b * TLEN;
        for (int t = lane; t < TLEN; t += 64)
            pout[t] = (float)path_sh[t];
    }
}

// ============ TIER 2 fallback: round-4 split kernel (proven 375 us) ============
__global__ __launch_bounds__(64) void crf_split4(
    const float* __restrict__ feats, const float* __restrict__ trans,
    const int* __restrict__ tags, float* __restrict__ out,
    unsigned char* __restrict__ bp_g)
{
    const int lane = threadIdx.x;
    const bool act = lane < KS;

    __shared__ float buf[2][64];
    __shared__ unsigned char path_sh[TLEN];
    __shared__ __align__(16) unsigned char seg[64 * KS];

    if (blockIdx.x < BN) {
        const int b = blockIdx.x;
        const float* fb = feats + (size_t)b * TLEN * KS;
        const int*   tb = tags + (size_t)b * TLEN;

        float Erow[KS];
        {
            const float* tr = trans + (act ? lane : 0) * KS;
            #pragma unroll
            for (int p = 0; p < KS; ++p) {
                float tv = act ? tr[p] : NEGV;
                if (lane == START_S) tv = NEGV;
                if (p == STOP_S)     tv = NEGV;
                Erow[p] = __expf(tv);
            }
        }
        float tstart = act ? trans[lane * KS + START_S] : NEGV;
        if (lane == START_S) tstart = NEGV;

        float alpha = (act ? fb[lane] : -INFINITY) + tstart;

        auto fstep = [&](float emv, int t) {
            float s  = bcast_lane0(alpha);
            float ue = __expf(alpha - s);
            const int bsel = t & 1;
            buf[bsel][lane] = ue;
            __syncthreads();
            const float4* uu = (const float4*)buf[bsel];
            v2f acc0 = {0.f, 0.f}, acc1 = {0.f, 0.f};
            #pragma unroll
            for (int g = 0; g < KS / 4; ++g) {
                float4 u = uu[g];
                v2f ua = {u.x, u.y}, ub = {u.z, u.w};
                v2f ea = {Erow[4 * g + 0], Erow[4 * g + 1]};
                v2f eb = {Erow[4 * g + 2], Erow[4 * g + 3]};
                acc0 = __builtin_elementwise_fma(ua, ea, acc0);
                acc1 = __builtin_elementwise_fma(ub, eb, acc1);
            }
            alpha = emv + s + __logf((acc0.x + acc0.y) + (acc1.x + acc1.y));
        };

        float em[PF];
        #pragma unroll
        for (int j = 0; j < PF; ++j)
            em[j] = act ? fb[(1 + j) * KS + lane] : -INFINITY;
        for (int c = 0; c < 63; ++c) {
            const int t0 = 1 + c * PF;
            float em_n[PF];
            #pragma unroll
            for (int j = 0; j < PF; ++j) {
                int tf = t0 + PF + j;
                em_n[j] = (act && tf < TLEN) ? fb[tf * KS + lane] : -INFINITY;
            }
            #pragma unroll
            for (int j = 0; j < PF; ++j) fstep(em[j], t0 + j);
            #pragma unroll
            for (int j = 0; j < PF; ++j) em[j] = em_n[j];
        }
        #pragma unroll
        for (int j = 0; j < 7; ++j) fstep(em[j], 505 + j);

        float tstop = act ? trans[STOP_S * KS + lane] : NEGV;
        if (lane == STOP_S) tstop = NEGV;
        float z = alpha + tstop;
        float mz = z;
        #pragma unroll
        for (int off = 32; off; off >>= 1)
            mz = fmaxf(mz, __shfl_xor(mz, off, 64));
        float se = __expf(z - mz);
        #pragma unroll
        for (int off = 32; off; off >>= 1)
            se += __shfl_xor(se, off, 64);
        float logZ = mz + __logf(se);

        float g = 0.0f;
        for (int t = lane; t < TLEN; t += 64) {
            int tg = tb[t];
            int pg = (t == 0) ? START_S : tb[t - 1];
            g += fb[t * KS + tg] + trans[tg * KS + pg];
        }
        #pragma unroll
        for (int off = 32; off; off >>= 1)
            g += __shfl_xor(g, off, 64);
        g += trans[STOP_S * KS + tb[TLEN - 1]];

        if (lane == 0) out[b] = logZ - g;
    } else {
        const int b = blockIdx.x - BN;
        const float* fb = feats + (size_t)b * TLEN * KS;
        unsigned char* bpb = bp_g + (size_t)b * TLEN * KS;

        float Trow[KS];
        {
            const float* tr = trans + (act ? lane : 0) * KS;
            #pragma unroll
            for (int p = 0; p < KS; ++p) {
                float tv = act ? tr[p] : NEGV;
                if (lane == START_S) tv = NEGV;
                if (p == STOP_S)     tv = NEGV;
                Trow[p] = tv;
            }
        }

        float vit = (lane == START_S) ? 0.0f : NEGV;

        auto vstep = [&](float emv, int t) {
            const int bsel = t & 1;
            buf[bsel][lane] = vit;
            __syncthreads();
            const float4* ww = (const float4*)buf[bsel];
            float bs[12]; int ib[12];
            #pragma unroll
            for (int g = 0; g < KS / 4; ++g) {
                float4 w = ww[g];
                v2f wa = {w.x, w.y}, wb = {w.z, w.w};
                v2f ta = {Trow[4 * g + 0], Trow[4 * g + 1]};
                v2f tc = {Trow[4 * g + 2], Trow[4 * g + 3]};
                v2f sa = wa + ta;
                v2f sb = wb + tc;
                float m01 = fmaxf(sa.x, sa.y); int i01 = (sa.y > sa.x) ? 4 * g + 1 : 4 * g + 0;
                float m23 = fmaxf(sb.x, sb.y); int i23 = (sb.y > sb.x) ? 4 * g + 3 : 4 * g + 2;
                bs[g] = fmaxf(m01, m23);       ib[g] = (m23 > m01) ? i23 : i01;
            }
            #pragma unroll
            for (int st = 0; st < 6; ++st) {
                float a = bs[2 * st], c2 = bs[2 * st + 1];
                int ia = ib[2 * st], ic = ib[2 * st + 1];
                bs[st] = fmaxf(a, c2); ib[st] = (c2 > a) ? ic : ia;
            }
            #pragma unroll
            for (int st = 0; st < 3; ++st) {
                float a = bs[2 * st], c2 = bs[2 * st + 1];
                int ia = ib[2 * st], ic = ib[2 * st + 1];
                bs[st] = fmaxf(a, c2); ib[st] = (c2 > a) ? ic : ia;
            }
            float best = fmaxf(bs[0], bs[1]);
            int   bi   = (bs[1] > bs[0]) ? ib[1] : ib[0];
            bi   = (bs[2] > best) ? ib[2] : bi;
            best = fmaxf(best, bs[2]);
            if (act) bpb[t * KS + lane] = (unsigned char)bi;
            vit = best + emv;
        };

        float em[PF];
        #pragma unroll
        for (int j = 0; j < PF; ++j)
            em[j] = act ? fb[j * KS + lane] : 0.0f;
        for (int c = 0; c < 64; ++c) {
            const int t0 = c * PF;
            float em_n[PF];
            if (c < 63) {
                #pragma unroll
                for (int j = 0; j < PF; ++j)
                    em_n[j] = act ? fb[(t0 + PF + j) * KS + lane] : 0.0f;
            }
            #pragma unroll
            for (int j = 0; j < PF; ++j) vstep(em[j], t0 + j);
            if (c < 63) {
                #pragma unroll
                for (int j = 0; j < PF; ++j) em[j] = em_n[j];
            }
        }

        float tstop = act ? trans[STOP_S * KS + lane] : NEGV;
        if (lane == STOP_S) tstop = NEGV;
        float term = act ? (vit + tstop) : -3.0e38f;
        float bv = term;
        int   bidx = act ? lane : 9999;
        wargmax(bv, bidx);
        if (lane == 0) out[BN + b] = bv;

        int tag = bidx;
        for (int s = 7; s >= 0; --s) {
            const float4* src = (const float4*)(bpb + s * 64 * KS);
            float4* dst = (float4*)seg;
            #pragma unroll
            for (int i = 0; i < 3; ++i)
                dst[lane + 64 * i] = src[lane + 64 * i];
            __syncthreads();
            for (int t = 63; t >= 0; --t) {
                path_sh[s * 64 + t] = (unsigned char)tag;
                tag = seg[t * KS + tag];
            }
            __syncthreads();
        }
        float* pout = out + 2 * BN + (size_t)b * TLEN;
        for (int t = lane; t < TLEN; t += 64)
            pout[t] = (float)path_sh[t];
    }
}

extern "C" void kernel_launch(void* const* d_in, const int* in_sizes, int n_in,
                              void* d_out, int out_size, void* d_ws, size_t ws_size,
                              hipStream_t stream) {
    const float* feats = (const float*)d_in[0];
    const float* trans = (const float*)d_in[1];
    const int*   tags  = (const int*)d_in[2];
    float*       out   = (float*)d_out;
    (void)in_sizes; (void)n_in; (void)out_size;

    const size_t needV = (size_t)BN * TLEN * KS * sizeof(float);  // 100.7 MB
    const size_t needB = (size_t)BN * TLEN * KS;                  // 25.2 MB
    if (ws_size >= needV) {
        crf9<<<dim3(2 * BN), dim3(64), 0, stream>>>(feats, trans, tags, out,
                                                    (float*)d_ws);
    } else if (ws_size >= needB) {
        crf_split4<<<dim3(2 * BN), dim3(64), 0, stream>>>(feats, trans, tags, out,
                                                          (unsigned char*)d_ws);
    } else {
        crf_split4<<<dim3(2 * BN), dim3(64), 0, stream>>>(feats, trans, tags, out,
                                                          (unsigned char*)d_ws);
    }
}

// Round 2
// 447.199 us; speedup vs baseline: 1.0665x; 1.0665x over previous
//
#include <hip/hip_runtime.h>
#include <math.h>

#define KS 48
#define TLEN 512
#define BN 1024
#define START_S 46
#define STOP_S 47
#define NEGV -10000.0f
#define PF 8   // emission prefetch depth

typedef float v2f __attribute__((ext_vector_type(2)));

__device__ __forceinline__ float bcast_lane0(float v) {
    return __builtin_bit_cast(float, __builtin_amdgcn_readfirstlane(__builtin_bit_cast(int, v)));
}

// wave argmax, first-index tie-break (matches jnp.argmax; validated rounds 1-7)
__device__ __forceinline__ void wargmax(float& bv, int& bi) {
    #pragma unroll
    for (int off = 32; off; off >>= 1) {
        float ov = __shfl_xor(bv, off, 64);
        int   oi = __shfl_xor(bi, off, 64);
        if (ov > bv || (ov == bv && oi < bi)) { bv = ov; bi = oi; }
    }
}

// grid = 2048, 1-wave blocks.
// ROUND-9 CHANGE (post-mortem of rounds 7/8): occupancy integral shows forward
// retires at ~0.35*T -> viterbi owns the critical path, and its ~250us tail is
// the B-row (vw) float store + reload + ballot backtrace (~1200 cy/step serial).
// Replace with split4's PROVEN argmax-in-scan (first-index tie-break tree,
// ~35 extra VALU/step -- free under a latency-bound scan) + 1-byte/state/step
// backpointers (25 MB vs 100 MB) + LDS chunked pointer-chase backtrace
// (~120cy ds_read chain, ~25us total). Forward branch: bit-identical round-0.
__global__ __launch_bounds__(64) void crf10(
    const float* __restrict__ feats,   // [B, T, K]
    const float* __restrict__ trans,   // [K, K]  trans[next, prev]
    const int*   __restrict__ tags,    // [B, T]
    float*       __restrict__ out,     // [B] nll | [B] path_score | [B*T] paths
    unsigned char* __restrict__ bp_g)  // [B, T, K] backpointer bytes
{
    const int lane = threadIdx.x;
    const bool act = lane < KS;

    __shared__ float xbuf[64];                     // state exchange (single buffer:
                                                   // in-order DS => no WAR hazard)
    __shared__ __align__(16) unsigned char seg[64 * KS];   // 3 KB backtrace chunk
    __shared__ unsigned char path_sh[TLEN];

    if (blockIdx.x < BN) {
        // ================= FORWARD (round-0 bits, verbatim) ====================
        const int b = blockIdx.x;
        const float* fb = feats + (size_t)b * TLEN * KS;
        const int*   tb = tags + (size_t)b * TLEN;

        float Erow[KS];   // exp(masked trans[next=lane][p]); exp(-10000)==0
        {
            const float* tr = trans + (act ? lane : 0) * KS;
            #pragma unroll
            for (int p = 0; p < KS; ++p) {
                float tv = act ? tr[p] : NEGV;
                if (lane == START_S) tv = NEGV;
                if (p == STOP_S)     tv = NEGV;
                Erow[p] = __expf(tv);
            }
        }
        float tstart = act ? trans[lane * KS + START_S] : NEGV;
        if (lane == START_S) tstart = NEGV;

        float alpha = (act ? fb[lane] : -INFINITY) + tstart;   // t=0 peeled, exact

        auto fstep = [&](float emv) {
            float s  = bcast_lane0(alpha);       // lane-0 alpha finite: valid shift
            float ue = __expf(alpha - s);        // -inf lanes -> 0
            xbuf[lane] = ue;                     // same-wave in-order LDS: no barrier
            const float4* uu = (const float4*)xbuf;
            v2f acc0 = {0.f, 0.f}, acc1 = {0.f, 0.f};
            #pragma unroll
            for (int g = 0; g < KS / 4; ++g) {
                float4 u = uu[g];
                v2f ua = {u.x, u.y}, ub = {u.z, u.w};
                v2f ea = {Erow[4 * g + 0], Erow[4 * g + 1]};
                v2f eb = {Erow[4 * g + 2], Erow[4 * g + 3]};
                acc0 = __builtin_elementwise_fma(ua, ea, acc0);
                acc1 = __builtin_elementwise_fma(ub, eb, acc1);
            }
            alpha = emv + s + __logf((acc0.x + acc0.y) + (acc1.x + acc1.y));
        };

        float em[PF];
        #pragma unroll
        for (int j = 0; j < PF; ++j)
            em[j] = act ? fb[(1 + j) * KS + lane] : -INFINITY;
        for (int c = 0; c < 63; ++c) {
            const int t0 = 1 + c * PF;
            float em_n[PF];
            #pragma unroll
            for (int j = 0; j < PF; ++j) {
                int tf = t0 + PF + j;
                em_n[j] = (act && tf < TLEN) ? fb[tf * KS + lane] : -INFINITY;
            }
            #pragma unroll
            for (int j = 0; j < PF; ++j) fstep(em[j]);
            #pragma unroll
            for (int j = 0; j < PF; ++j) em[j] = em_n[j];
        }
        #pragma unroll
        for (int j = 0; j < 7; ++j) fstep(em[j]);

        float tstop = act ? trans[STOP_S * KS + lane] : NEGV;
        if (lane == STOP_S) tstop = NEGV;
        float z = alpha + tstop;
        float mz = z;
        #pragma unroll
        for (int off = 32; off; off >>= 1)
            mz = fmaxf(mz, __shfl_xor(mz, off, 64));
        float se = __expf(z - mz);
        #pragma unroll
        for (int off = 32; off; off >>= 1)
            se += __shfl_xor(se, off, 64);
        float logZ = mz + __logf(se);

        float g = 0.0f;
        for (int t = lane; t < TLEN; t += 64) {
            int tg = tb[t];
            int pg = (t == 0) ? START_S : tb[t - 1];
            g += fb[t * KS + tg] + trans[tg * KS + pg];
        }
        #pragma unroll
        for (int off = 32; off; off >>= 1)
            g += __shfl_xor(g, off, 64);
        g += trans[STOP_S * KS + tb[TLEN - 1]];

        if (lane == 0) out[b] = logZ - g;
    } else {
        // ======== VITERBI: argmax-in-scan (split4 tree) + byte backpointers ====
        const int b = blockIdx.x - BN;
        const float* fb = feats + (size_t)b * TLEN * KS;
        unsigned char* bpb = bp_g + (size_t)b * TLEN * KS;

        float Trow[KS];   // masked trans[next=lane][p] — reference's exact add
        {
            const float* tr = trans + (act ? lane : 0) * KS;
            #pragma unroll
            for (int p = 0; p < KS; ++p) {
                float tv = act ? tr[p] : NEGV;
                if (lane == START_S) tv = NEGV;
                if (p == STOP_S)     tv = NEGV;
                Trow[p] = tv;
            }
        }

        float vit = (lane == START_S) ? 0.0f : NEGV;

        // split4's validated first-index argmax tree (pairs keep the earlier
        // index on ties; cross-group merges promote only on strict >).
        auto vstep = [&](float emv, int t) {
            xbuf[lane] = vit;                    // in-order LDS, no barrier
            const float4* ww = (const float4*)xbuf;
            float bs[12]; int ib[12];
            #pragma unroll
            for (int g = 0; g < KS / 4; ++g) {
                float4 w = ww[g];
                v2f wa = {w.x, w.y}, wb = {w.z, w.w};
                v2f ta = {Trow[4 * g + 0], Trow[4 * g + 1]};
                v2f tc = {Trow[4 * g + 2], Trow[4 * g + 3]};
                v2f sa = wa + ta;
                v2f sb = wb + tc;
                float m01 = fmaxf(sa.x, sa.y); int i01 = (sa.y > sa.x) ? 4 * g + 1 : 4 * g + 0;
                float m23 = fmaxf(sb.x, sb.y); int i23 = (sb.y > sb.x) ? 4 * g + 3 : 4 * g + 2;
                bs[g] = fmaxf(m01, m23);       ib[g] = (m23 > m01) ? i23 : i01;
            }
            #pragma unroll
            for (int st = 0; st < 6; ++st) {
                float a = bs[2 * st], c2 = bs[2 * st + 1];
                int ia = ib[2 * st], ic = ib[2 * st + 1];
                bs[st] = fmaxf(a, c2); ib[st] = (c2 > a) ? ic : ia;
            }
            #pragma unroll
            for (int st = 0; st < 3; ++st) {
                float a = bs[2 * st], c2 = bs[2 * st + 1];
                int ia = ib[2 * st], ic = ib[2 * st + 1];
                bs[st] = fmaxf(a, c2); ib[st] = (c2 > a) ? ic : ia;
            }
            float best = fmaxf(bs[0], bs[1]);
            int   bi   = (bs[1] > bs[0]) ? ib[1] : ib[0];
            bi   = (bs[2] > best) ? ib[2] : bi;
            best = fmaxf(best, bs[2]);
            if (act) bpb[t * KS + lane] = (unsigned char)bi;  // 48B = one line
            vit = best + emv;
        };

        float em[PF];
        #pragma unroll
        for (int j = 0; j < PF; ++j)
            em[j] = act ? fb[j * KS + lane] : 0.0f;
        for (int c = 0; c < 64; ++c) {           // 512 = 64*8 exactly
            const int t0 = c * PF;
            float em_n[PF];
            if (c < 63) {
                #pragma unroll
                for (int j = 0; j < PF; ++j)
                    em_n[j] = act ? fb[(t0 + PF + j) * KS + lane] : 0.0f;
            }
            #pragma unroll
            for (int j = 0; j < PF; ++j) vstep(em[j], t0 + j);
            if (c < 63) {
                #pragma unroll
                for (int j = 0; j < PF; ++j) em[j] = em_n[j];
            }
        }

        // drain byte stores before re-reading them in the backtrace
        asm volatile("s_waitcnt vmcnt(0)" ::: "memory");

        float tstop = act ? trans[STOP_S * KS + lane] : NEGV;
        if (lane == STOP_S) tstop = NEGV;
        float term = act ? (vit + tstop) : -3.0e38f;
        float bv = term;
        int   bidx = act ? lane : 9999;
        wargmax(bv, bidx);
        if (lane == 0) out[BN + b] = bv;

        // ---- chunked LDS pointer-chase backtrace (split4, proven) ----
        int tag = bidx;
        for (int s = 7; s >= 0; --s) {
            const float4* src = (const float4*)(bpb + s * 64 * KS);
            float4* dst = (float4*)seg;
            #pragma unroll
            for (int i = 0; i < 3; ++i)
                dst[lane + 64 * i] = src[lane + 64 * i];   // 3 KB chunk
            __syncthreads();
            for (int t = 63; t >= 0; --t) {
                path_sh[s * 64 + t] = (unsigned char)tag;  // tag at time s*64+t
                tag = seg[t * KS + tag];                   // -> tag at t-1
            }
            __syncthreads();
        }
        float* pout = out + 2 * BN + (size_t)b * TLEN;
        for (int t = lane; t < TLEN; t += 64)
            pout[t] = (float)path_sh[t];
    }
}

extern "C" void kernel_launch(void* const* d_in, const int* in_sizes, int n_in,
                              void* d_out, int out_size, void* d_ws, size_t ws_size,
                              hipStream_t stream) {
    const float* feats = (const float*)d_in[0];
    const float* trans = (const float*)d_in[1];
    const int*   tags  = (const int*)d_in[2];
    float*       out   = (float*)d_out;
    (void)in_sizes; (void)n_in; (void)out_size; (void)ws_size;

    // needs (size_t)BN*TLEN*KS = 25.2 MB of workspace; observed ws_size >= 100 MB
    crf10<<<dim3(2 * BN), dim3(64), 0, stream>>>(feats, trans, tags, out,
                                                 (unsigned char*)d_ws);
}

// Round 3
// 441.514 us; speedup vs baseline: 1.0803x; 1.0129x over previous
//
#include <hip/hip_runtime.h>
#include <math.h>

#define KS 48
#define TLEN 512
#define BN 1024
#define START_S 46
#define STOP_S 47
#define NEGV -10000.0f
#define PF 8   // emission prefetch depth

typedef float v2f __attribute__((ext_vector_type(2)));

__device__ __forceinline__ float bcast_lane0(float v) {
    return __builtin_bit_cast(float, __builtin_amdgcn_readfirstlane(__builtin_bit_cast(int, v)));
}

// wave argmax, first-index tie-break (matches jnp.argmax; validated rounds 1-7)
__device__ __forceinline__ void wargmax(float& bv, int& bi) {
    #pragma unroll
    for (int off = 32; off; off >>= 1) {
        float ov = __shfl_xor(bv, off, 64);
        int   oi = __shfl_xor(bi, off, 64);
        if (ov > bv || (ov == bv && oi < bi)) { bv = ov; bi = oi; }
    }
}

// grid = 2048, 1-wave blocks.
// ROUND-10 CHANGE (store-latency theory): cross-round elimination left exactly
// one structural asymmetry between the ~560cy/step forward scan and the
// ~1550cy/step viterbi scan: the per-step global store. vmcnt retires IN ORDER,
// so each chunk's em-prefetch loads retire only after all older backpointer
// stores complete -> every chunk boundary inherits store-completion latency.
// Fix: backpointers go to an LDS ring (ds_write_b8/step, same-wave in-order),
// flushed once per 64 steps as 3 dwordx4 bursts (groups 0-6); group 7 stays
// resident and seeds the backtrace. 512 global stores/wave -> 21.
__global__ __launch_bounds__(64) void crf11(
    const float* __restrict__ feats,   // [B, T, K]
    const float* __restrict__ trans,   // [K, K]  trans[next, prev]
    const int*   __restrict__ tags,    // [B, T]
    float*       __restrict__ out,     // [B] nll | [B] path_score | [B*T] paths
    unsigned char* __restrict__ bp_g)  // [B, T, K] backpointer bytes (groups 0-6)
{
    const int lane = threadIdx.x;
    const bool act = lane < KS;

    __shared__ float xbuf[64];                     // state exchange (single buffer:
                                                   // in-order DS => no WAR hazard)
    __shared__ __align__(16) unsigned char seg[64 * KS];   // 3 KB bp ring / chunk
    __shared__ unsigned char path_sh[TLEN];

    if (blockIdx.x < BN) {
        // ================= FORWARD (round-0 bits, verbatim) ====================
        const int b = blockIdx.x;
        const float* fb = feats + (size_t)b * TLEN * KS;
        const int*   tb = tags + (size_t)b * TLEN;

        float Erow[KS];   // exp(masked trans[next=lane][p]); exp(-10000)==0
        {
            const float* tr = trans + (act ? lane : 0) * KS;
            #pragma unroll
            for (int p = 0; p < KS; ++p) {
                float tv = act ? tr[p] : NEGV;
                if (lane == START_S) tv = NEGV;
                if (p == STOP_S)     tv = NEGV;
                Erow[p] = __expf(tv);
            }
        }
        float tstart = act ? trans[lane * KS + START_S] : NEGV;
        if (lane == START_S) tstart = NEGV;

        float alpha = (act ? fb[lane] : -INFINITY) + tstart;   // t=0 peeled, exact

        auto fstep = [&](float emv) {
            float s  = bcast_lane0(alpha);       // lane-0 alpha finite: valid shift
            float ue = __expf(alpha - s);        // -inf lanes -> 0
            xbuf[lane] = ue;                     // same-wave in-order LDS: no barrier
            const float4* uu = (const float4*)xbuf;
            v2f acc0 = {0.f, 0.f}, acc1 = {0.f, 0.f};
            #pragma unroll
            for (int g = 0; g < KS / 4; ++g) {
                float4 u = uu[g];
                v2f ua = {u.x, u.y}, ub = {u.z, u.w};
                v2f ea = {Erow[4 * g + 0], Erow[4 * g + 1]};
                v2f eb = {Erow[4 * g + 2], Erow[4 * g + 3]};
                acc0 = __builtin_elementwise_fma(ua, ea, acc0);
                acc1 = __builtin_elementwise_fma(ub, eb, acc1);
            }
            alpha = emv + s + __logf((acc0.x + acc0.y) + (acc1.x + acc1.y));
        };

        float em[PF];
        #pragma unroll
        for (int j = 0; j < PF; ++j)
            em[j] = act ? fb[(1 + j) * KS + lane] : -INFINITY;
        for (int c = 0; c < 63; ++c) {
            const int t0 = 1 + c * PF;
            float em_n[PF];
            #pragma unroll
            for (int j = 0; j < PF; ++j) {
                int tf = t0 + PF + j;
                em_n[j] = (act && tf < TLEN) ? fb[tf * KS + lane] : -INFINITY;
            }
            #pragma unroll
            for (int j = 0; j < PF; ++j) fstep(em[j]);
            #pragma unroll
            for (int j = 0; j < PF; ++j) em[j] = em_n[j];
        }
        #pragma unroll
        for (int j = 0; j < 7; ++j) fstep(em[j]);

        float tstop = act ? trans[STOP_S * KS + lane] : NEGV;
        if (lane == STOP_S) tstop = NEGV;
        float z = alpha + tstop;
        float mz = z;
        #pragma unroll
        for (int off = 32; off; off >>= 1)
            mz = fmaxf(mz, __shfl_xor(mz, off, 64));
        float se = __expf(z - mz);
        #pragma unroll
        for (int off = 32; off; off >>= 1)
            se += __shfl_xor(se, off, 64);
        float logZ = mz + __logf(se);

        float g = 0.0f;
        for (int t = lane; t < TLEN; t += 64) {
            int tg = tb[t];
            int pg = (t == 0) ? START_S : tb[t - 1];
            g += fb[t * KS + tg] + trans[tg * KS + pg];
        }
        #pragma unroll
        for (int off = 32; off; off >>= 1)
            g += __shfl_xor(g, off, 64);
        g += trans[STOP_S * KS + tb[TLEN - 1]];

        if (lane == 0) out[b] = logZ - g;
    } else {
        // ======== VITERBI: argmax-in-scan + LDS-buffered backpointers ==========
        const int b = blockIdx.x - BN;
        const float* fb = feats + (size_t)b * TLEN * KS;
        unsigned char* bpb = bp_g + (size_t)b * TLEN * KS;

        float Trow[KS];   // masked trans[next=lane][p] — reference's exact add
        {
            const float* tr = trans + (act ? lane : 0) * KS;
            #pragma unroll
            for (int p = 0; p < KS; ++p) {
                float tv = act ? tr[p] : NEGV;
                if (lane == START_S) tv = NEGV;
                if (p == STOP_S)     tv = NEGV;
                Trow[p] = tv;
            }
        }

        float vit = (lane == START_S) ? 0.0f : NEGV;

        // split4's validated first-index argmax tree (pairs keep the earlier
        // index on ties; cross-group merges promote only on strict >).
        auto vstep = [&](float emv, int t) {
            xbuf[lane] = vit;                    // in-order LDS, no barrier
            const float4* ww = (const float4*)xbuf;
            float bs[12]; int ib[12];
            #pragma unroll
            for (int g = 0; g < KS / 4; ++g) {
                float4 w = ww[g];
                v2f wa = {w.x, w.y}, wb = {w.z, w.w};
                v2f ta = {Trow[4 * g + 0], Trow[4 * g + 1]};
                v2f tc = {Trow[4 * g + 2], Trow[4 * g + 3]};
                v2f sa = wa + ta;
                v2f sb = wb + tc;
                float m01 = fmaxf(sa.x, sa.y); int i01 = (sa.y > sa.x) ? 4 * g + 1 : 4 * g + 0;
                float m23 = fmaxf(sb.x, sb.y); int i23 = (sb.y > sb.x) ? 4 * g + 3 : 4 * g + 2;
                bs[g] = fmaxf(m01, m23);       ib[g] = (m23 > m01) ? i23 : i01;
            }
            #pragma unroll
            for (int st = 0; st < 6; ++st) {
                float a = bs[2 * st], c2 = bs[2 * st + 1];
                int ia = ib[2 * st], ic = ib[2 * st + 1];
                bs[st] = fmaxf(a, c2); ib[st] = (c2 > a) ? ic : ia;
            }
            #pragma unroll
            for (int st = 0; st < 3; ++st) {
                float a = bs[2 * st], c2 = bs[2 * st + 1];
                int ia = ib[2 * st], ic = ib[2 * st + 1];
                bs[st] = fmaxf(a, c2); ib[st] = (c2 > a) ? ic : ia;
            }
            float best = fmaxf(bs[0], bs[1]);
            int   bi   = (bs[1] > bs[0]) ? ib[1] : ib[0];
            bi   = (bs[2] > best) ? ib[2] : bi;
            best = fmaxf(best, bs[2]);
            if (act) seg[(t & 63) * KS + lane] = (unsigned char)bi;  // LDS ring,
            vit = best + emv;                                        // no vmem op
        };

        float em[PF];
        #pragma unroll
        for (int j = 0; j < PF; ++j)
            em[j] = act ? fb[j * KS + lane] : 0.0f;
        for (int c = 0; c < 64; ++c) {           // 512 = 64*8 exactly
            const int t0 = c * PF;
            float em_n[PF];
            if (c < 63) {
                #pragma unroll
                for (int j = 0; j < PF; ++j)
                    em_n[j] = act ? fb[(t0 + PF + j) * KS + lane] : 0.0f;
            }
            #pragma unroll
            for (int j = 0; j < PF; ++j) vstep(em[j], t0 + j);
            // flush completed 64-step group (groups 0..6; group 7 stays in LDS).
            // same-wave in-order DS: ring writes above are visible, and these
            // reads complete before the next group's ds_write_b8 overwrites.
            if ((c & 7) == 7 && c < 56) {
                const float4* s4 = (const float4*)seg;
                float4* d4 = (float4*)(bpb + (size_t)(c - 7) * PF * KS);
                #pragma unroll
                for (int i = 0; i < 3; ++i)
                    d4[lane + 64 * i] = s4[lane + 64 * i];   // 3 KB burst
            }
            if (c < 63) {
                #pragma unroll
                for (int j = 0; j < PF; ++j) em[j] = em_n[j];
            }
        }

        // drain flush stores before re-reading them in the backtrace
        asm volatile("s_waitcnt vmcnt(0)" ::: "memory");

        float tstop = act ? trans[STOP_S * KS + lane] : NEGV;
        if (lane == STOP_S) tstop = NEGV;
        float term = act ? (vit + tstop) : -3.0e38f;
        float bv = term;
        int   bidx = act ? lane : 9999;
        wargmax(bv, bidx);
        if (lane == 0) out[BN + b] = bv;

        // ---- chunked LDS pointer-chase backtrace ----
        // group 7 (t=448..511) is already resident in seg: chase it first.
        int tag = bidx;
        for (int t = 63; t >= 0; --t) {
            path_sh[448 + t] = (unsigned char)tag;
            tag = seg[t * KS + tag];
        }
        for (int s = 6; s >= 0; --s) {
            float4 tmp[3];
            const float4* src = (const float4*)(bpb + (size_t)s * 64 * KS);
            #pragma unroll
            for (int i = 0; i < 3; ++i)
                tmp[i] = src[lane + 64 * i];
            // same-wave in-order DS: prior chase reads precede these writes
            float4* dst = (float4*)seg;
            #pragma unroll
            for (int i = 0; i < 3; ++i)
                dst[lane + 64 * i] = tmp[i];
            for (int t = 63; t >= 0; --t) {
                path_sh[s * 64 + t] = (unsigned char)tag;  // tag at time s*64+t
                tag = seg[t * KS + tag];                   // -> tag at t-1
            }
        }
        __syncthreads();   // single wave: drains LDS before the read-back
        float* pout = out + 2 * BN + (size_t)b * TLEN;
        for (int t = lane; t < TLEN; t += 64)
            pout[t] = (float)path_sh[t];
    }
}

extern "C" void kernel_launch(void* const* d_in, const int* in_sizes, int n_in,
                              void* d_out, int out_size, void* d_ws, size_t ws_size,
                              hipStream_t stream) {
    const float* feats = (const float*)d_in[0];
    const float* trans = (const float*)d_in[1];
    const int*   tags  = (const int*)d_in[2];
    float*       out   = (float*)d_out;
    (void)in_sizes; (void)n_in; (void)out_size; (void)ws_size;

    // needs (size_t)BN*TLEN*KS = 25.2 MB of workspace; observed ws_size >= 100 MB
    crf11<<<dim3(2 * BN), dim3(64), 0, stream>>>(feats, trans, tags, out,
                                                 (unsigned char*)d_ws);
}

// Round 4
// 436.566 us; speedup vs baseline: 1.0925x; 1.0113x over previous
//
#include <hip/hip_runtime.h>
#include <math.h>

#define KS 48
#define TLEN 512
#define BN 1024
#define START_S 46
#define STOP_S 47
#define NEGV -10000.0f
#define PF 8   // emission prefetch depth

typedef float v2f __attribute__((ext_vector_type(2)));

__device__ __forceinline__ float bcast_lane0(float v) {
    return __builtin_bit_cast(float, __builtin_amdgcn_readfirstlane(__builtin_bit_cast(int, v)));
}

// wave argmax, first-index tie-break (matches jnp.argmax; validated rounds 1-7)
__device__ __forceinline__ void wargmax(float& bv, int& bi) {
    #pragma unroll
    for (int off = 32; off; off >>= 1) {
        float ov = __shfl_xor(bv, off, 64);
        int   oi = __shfl_xor(bi, off, 64);
        if (ov > bv || (ov == bv && oi < bi)) { bv = ov; bi = oi; }
    }
}

// grid = 2048, 1-wave blocks.
// ROUND-11 CHANGE (schedule theory): 360us = 1688 cy/step matches 12 ds_read_b128
// each paying its FULL ~120cy latency serially (compiler interleaves read->use
// because the accumulator chain is serial and the reads alias the ds_write).
// Fix: batch-load all 12 float4s into named registers behind sched_barrier(0)
// fences, then run the IDENTICAL fma/max trees. One batched lgkmcnt wait
// (~190cy) replaces 12 serial ones (~1440cy). Arithmetic is bit-for-bit the
// validated round-0/round-3 order: only s_waitcnt placement may change.
__global__ __launch_bounds__(64) void crf12(
    const float* __restrict__ feats,   // [B, T, K]
    const float* __restrict__ trans,   // [K, K]  trans[next, prev]
    const int*   __restrict__ tags,    // [B, T]
    float*       __restrict__ out,     // [B] nll | [B] path_score | [B*T] paths
    unsigned char* __restrict__ bp_g)  // [B, T, K] backpointer bytes (groups 0-6)
{
    const int lane = threadIdx.x;
    const bool act = lane < KS;

    __shared__ float xbuf[64];                     // state exchange (single buffer:
                                                   // in-order DS => no WAR hazard)
    __shared__ __align__(16) unsigned char seg[64 * KS];   // 3 KB bp ring / chunk
    __shared__ unsigned char path_sh[TLEN];

    if (blockIdx.x < BN) {
        // ================= FORWARD (round-0 arithmetic, batched loads) =========
        const int b = blockIdx.x;
        const float* fb = feats + (size_t)b * TLEN * KS;
        const int*   tb = tags + (size_t)b * TLEN;

        float Erow[KS];   // exp(masked trans[next=lane][p]); exp(-10000)==0
        {
            const float* tr = trans + (act ? lane : 0) * KS;
            #pragma unroll
            for (int p = 0; p < KS; ++p) {
                float tv = act ? tr[p] : NEGV;
                if (lane == START_S) tv = NEGV;
                if (p == STOP_S)     tv = NEGV;
                Erow[p] = __expf(tv);
            }
        }
        float tstart = act ? trans[lane * KS + START_S] : NEGV;
        if (lane == START_S) tstart = NEGV;

        float alpha = (act ? fb[lane] : -INFINITY) + tstart;   // t=0 peeled, exact

        auto fstep = [&](float emv) {
            float s  = bcast_lane0(alpha);       // lane-0 alpha finite: valid shift
            float ue = __expf(alpha - s);        // -inf lanes -> 0
            xbuf[lane] = ue;                     // same-wave in-order LDS: no barrier
            __builtin_amdgcn_sched_barrier(0);   // write stays before the reads
            const float4* uu = (const float4*)xbuf;
            float4 U[KS / 4];                    // static indices only (unrolled)
            #pragma unroll
            for (int g = 0; g < KS / 4; ++g)
                U[g] = uu[g];                    // 12 back-to-back ds_read_b128
            __builtin_amdgcn_sched_barrier(0);   // reads stay before the compute
            v2f acc0 = {0.f, 0.f}, acc1 = {0.f, 0.f};
            #pragma unroll
            for (int g = 0; g < KS / 4; ++g) {
                v2f ua = {U[g].x, U[g].y}, ub = {U[g].z, U[g].w};
                v2f ea = {Erow[4 * g + 0], Erow[4 * g + 1]};
                v2f eb = {Erow[4 * g + 2], Erow[4 * g + 3]};
                acc0 = __builtin_elementwise_fma(ua, ea, acc0);
                acc1 = __builtin_elementwise_fma(ub, eb, acc1);
            }
            alpha = emv + s + __logf((acc0.x + acc0.y) + (acc1.x + acc1.y));
        };

        float em[PF];
        #pragma unroll
        for (int j = 0; j < PF; ++j)
            em[j] = act ? fb[(1 + j) * KS + lane] : -INFINITY;
        for (int c = 0; c < 63; ++c) {
            const int t0 = 1 + c * PF;
            float em_n[PF];
            #pragma unroll
            for (int j = 0; j < PF; ++j) {
                int tf = t0 + PF + j;
                em_n[j] = (act && tf < TLEN) ? fb[tf * KS + lane] : -INFINITY;
            }
            #pragma unroll
            for (int j = 0; j < PF; ++j) fstep(em[j]);
            #pragma unroll
            for (int j = 0; j < PF; ++j) em[j] = em_n[j];
        }
        #pragma unroll
        for (int j = 0; j < 7; ++j) fstep(em[j]);

        float tstop = act ? trans[STOP_S * KS + lane] : NEGV;
        if (lane == STOP_S) tstop = NEGV;
        float z = alpha + tstop;
        float mz = z;
        #pragma unroll
        for (int off = 32; off; off >>= 1)
            mz = fmaxf(mz, __shfl_xor(mz, off, 64));
        float se = __expf(z - mz);
        #pragma unroll
        for (int off = 32; off; off >>= 1)
            se += __shfl_xor(se, off, 64);
        float logZ = mz + __logf(se);

        float g = 0.0f;
        for (int t = lane; t < TLEN; t += 64) {
            int tg = tb[t];
            int pg = (t == 0) ? START_S : tb[t - 1];
            g += fb[t * KS + tg] + trans[tg * KS + pg];
        }
        #pragma unroll
        for (int off = 32; off; off >>= 1)
            g += __shfl_xor(g, off, 64);
        g += trans[STOP_S * KS + tb[TLEN - 1]];

        if (lane == 0) out[b] = logZ - g;
    } else {
        // ======== VITERBI: argmax-in-scan + LDS ring bp, batched loads =========
        const int b = blockIdx.x - BN;
        const float* fb = feats + (size_t)b * TLEN * KS;
        unsigned char* bpb = bp_g + (size_t)b * TLEN * KS;

        float Trow[KS];   // masked trans[next=lane][p] — reference's exact add
        {
            const float* tr = trans + (act ? lane : 0) * KS;
            #pragma unroll
            for (int p = 0; p < KS; ++p) {
                float tv = act ? tr[p] : NEGV;
                if (lane == START_S) tv = NEGV;
                if (p == STOP_S)     tv = NEGV;
                Trow[p] = tv;
            }
        }

        float vit = (lane == START_S) ? 0.0f : NEGV;

        // split4's validated first-index argmax tree (pairs keep the earlier
        // index on ties; cross-group merges promote only on strict >).
        auto vstep = [&](float emv, int t) {
            xbuf[lane] = vit;                    // in-order LDS, no barrier
            __builtin_amdgcn_sched_barrier(0);
            const float4* ww = (const float4*)xbuf;
            float4 W[KS / 4];
            #pragma unroll
            for (int g = 0; g < KS / 4; ++g)
                W[g] = ww[g];                    // 12 back-to-back ds_read_b128
            __builtin_amdgcn_sched_barrier(0);
            float bs[12]; int ib[12];
            #pragma unroll
            for (int g = 0; g < KS / 4; ++g) {
                v2f wa = {W[g].x, W[g].y}, wb = {W[g].z, W[g].w};
                v2f ta = {Trow[4 * g + 0], Trow[4 * g + 1]};
                v2f tc = {Trow[4 * g + 2], Trow[4 * g + 3]};
                v2f sa = wa + ta;
                v2f sb = wb + tc;
                float m01 = fmaxf(sa.x, sa.y); int i01 = (sa.y > sa.x) ? 4 * g + 1 : 4 * g + 0;
                float m23 = fmaxf(sb.x, sb.y); int i23 = (sb.y > sb.x) ? 4 * g + 3 : 4 * g + 2;
                bs[g] = fmaxf(m01, m23);       ib[g] = (m23 > m01) ? i23 : i01;
            }
            #pragma unroll
            for (int st = 0; st < 6; ++st) {
                float a = bs[2 * st], c2 = bs[2 * st + 1];
                int ia = ib[2 * st], ic = ib[2 * st + 1];
                bs[st] = fmaxf(a, c2); ib[st] = (c2 > a) ? ic : ia;
            }
            #pragma unroll
            for (int st = 0; st < 3; ++st) {
                float a = bs[2 * st], c2 = bs[2 * st + 1];
                int ia = ib[2 * st], ic = ib[2 * st + 1];
                bs[st] = fmaxf(a, c2); ib[st] = (c2 > a) ? ic : ia;
            }
            float best = fmaxf(bs[0], bs[1]);
            int   bi   = (bs[1] > bs[0]) ? ib[1] : ib[0];
            bi   = (bs[2] > best) ? ib[2] : bi;
            best = fmaxf(best, bs[2]);
            if (act) seg[(t & 63) * KS + lane] = (unsigned char)bi;  // LDS ring,
            vit = best + emv;                                        // no vmem op
        };

        float em[PF];
        #pragma unroll
        for (int j = 0; j < PF; ++j)
            em[j] = act ? fb[j * KS + lane] : 0.0f;
        for (int c = 0; c < 64; ++c) {           // 512 = 64*8 exactly
            const int t0 = c * PF;
            float em_n[PF];
            if (c < 63) {
                #pragma unroll
                for (int j = 0; j < PF; ++j)
                    em_n[j] = act ? fb[(t0 + PF + j) * KS + lane] : 0.0f;
            }
            #pragma unroll
            for (int j = 0; j < PF; ++j) vstep(em[j], t0 + j);
            // flush completed 64-step group (groups 0..6; group 7 stays in LDS).
            if ((c & 7) == 7 && c < 56) {
                const float4* s4 = (const float4*)seg;
                float4* d4 = (float4*)(bpb + (size_t)(c - 7) * PF * KS);
                #pragma unroll
                for (int i = 0; i < 3; ++i)
                    d4[lane + 64 * i] = s4[lane + 64 * i];   // 3 KB burst
            }
            if (c < 63) {
                #pragma unroll
                for (int j = 0; j < PF; ++j) em[j] = em_n[j];
            }
        }

        // drain flush stores before re-reading them in the backtrace
        asm volatile("s_waitcnt vmcnt(0)" ::: "memory");

        float tstop = act ? trans[STOP_S * KS + lane] : NEGV;
        if (lane == STOP_S) tstop = NEGV;
        float term = act ? (vit + tstop) : -3.0e38f;
        float bv = term;
        int   bidx = act ? lane : 9999;
        wargmax(bv, bidx);
        if (lane == 0) out[BN + b] = bv;

        // ---- chunked LDS pointer-chase backtrace ----
        // group 7 (t=448..511) is already resident in seg: chase it first.
        int tag = bidx;
        for (int t = 63; t >= 0; --t) {
            path_sh[448 + t] = (unsigned char)tag;
            tag = seg[t * KS + tag];
        }
        for (int s = 6; s >= 0; --s) {
            float4 tmp[3];
            const float4* src = (const float4*)(bpb + (size_t)s * 64 * KS);
            #pragma unroll
            for (int i = 0; i < 3; ++i)
                tmp[i] = src[lane + 64 * i];
            // same-wave in-order DS: prior chase reads precede these writes
            float4* dst = (float4*)seg;
            #pragma unroll
            for (int i = 0; i < 3; ++i)
                dst[lane + 64 * i] = tmp[i];
            for (int t = 63; t >= 0; --t) {
                path_sh[s * 64 + t] = (unsigned char)tag;  // tag at time s*64+t
                tag = seg[t * KS + tag];                   // -> tag at t-1
            }
        }
        __syncthreads();   // single wave: drains LDS before the read-back
        float* pout = out + 2 * BN + (size_t)b * TLEN;
        for (int t = lane; t < TLEN; t += 64)
            pout[t] = (float)path_sh[t];
    }
}

extern "C" void kernel_launch(void* const* d_in, const int* in_sizes, int n_in,
                              void* d_out, int out_size, void* d_ws, size_t ws_size,
                              hipStream_t stream) {
    const float* feats = (const float*)d_in[0];
    const float* trans = (const float*)d_in[1];
    const int*   tags  = (const int*)d_in[2];
    float*       out   = (float*)d_out;
    (void)in_sizes; (void)n_in; (void)out_size; (void)ws_size;

    // needs (size_t)BN*TLEN*KS = 25.2 MB of workspace; observed ws_size >= 100 MB
    crf12<<<dim3(2 * BN), dim3(64), 0, stream>>>(feats, trans, tags, out,
                                                 (unsigned char*)d_ws);
}